// Round 11
// baseline (163.330 us; speedup 1.0000x reference)
//
#include <hip/hip_runtime.h>

#define H_IMG 128
#define W_IMG 128
#define NQ (H_IMG * W_IMG)
#define CIN 256
#define NH 8
#define NP 4
#define DH 32
#define LDSP 264  // padded LDS row stride (16-bit elems); 264%32=8 -> 2-way max aliasing (free)

typedef __bf16 bf16x4 __attribute__((ext_vector_type(4)));
typedef __bf16 bf16x8 __attribute__((ext_vector_type(8)));
typedef _Float16 f16x8 __attribute__((ext_vector_type(8)));
typedef float f32x4 __attribute__((ext_vector_type(4)));

// ---------------- weight prep: transpose to BT[N][K]; btv/btoa bf16, bto f16 -------
__global__ __launch_bounds__(256) void prep_weights(
    const float* __restrict__ Wval, const float* __restrict__ Wout,
    const float* __restrict__ Woff, const float* __restrict__ Wattn,
    const float* __restrict__ boff, const float* __restrict__ battn,
    __bf16* __restrict__ btv, _Float16* __restrict__ bto,
    __bf16* __restrict__ btoa, float* __restrict__ bias96) {
  int id = blockIdx.x * 256 + threadIdx.x;
  if (id < 256 * 256) {
    int n = id >> 8, k = id & 255;
    btv[n * 256 + k] = (__bf16)Wval[k * 256 + n];
    bto[n * 256 + k] = (_Float16)Wout[k * 256 + n];
  }
  if (id < 96 * 256) {
    int n = id >> 8, k = id & 255;
    float w = (n < 64) ? Woff[k * 64 + n] : Wattn[k * 32 + (n - 64)];
    btoa[n * 256 + k] = (__bf16)w;
  }
  if (id < 96) {
    bias96[id] = (id < 64) ? boff[id] : battn[id - 64];
  }
}

// ---------------- K1: v = value @ W_val + b_val (head-planar f16 out) --------------
// R10 structure (64-row/512-block identity mapping -> K2 XCD affinity intact;
// 512 threads -> 16 waves/CU; R10: -6 us). THIS ROUND: epilogue rewritten.
// Old: 32 scalar 2B stores/thread at MFMA-fragment-scattered addresses (per
// wave-store four disjoint 32B chunks; ~8M store instrs for 16 MB). New: stage the
// block's 64x256 f16 result through LDS in head-planar layout (reuses As, 32 KB),
// then 512 threads each emit one contiguous 64B run (4x f16x8; consecutive threads
// -> consecutive addresses; 4 KB contiguous per wave). v bytes/layout UNCHANGED.
__global__ __launch_bounds__(512, 2) void gemm_v(
    const float* __restrict__ A, const __bf16* __restrict__ BT,
    const float* __restrict__ bias, _Float16* __restrict__ v, int M) {
  const int t = threadIdx.x;
  const int lane = t & 63;
  const int wave = t >> 6;  // 0..7
  const int r = lane & 15;
  const int q = lane >> 4;
  const int gm0 = blockIdx.x * 64;
  const int wn = wave * 32;  // one 32-col head plane per wave

  __shared__ __bf16 As[64 * LDSP];
  _Float16* Asv = (_Float16*)As;  // epilogue: head-planar f16 tile [8*64][32] = 32 KB

  // stage A (64 x 256 fp32 -> bf16), 512 threads, coalesced, conflict-free
#pragma unroll
  for (int i = 0; i < 8; ++i) {
    int g = i * 512 + t;
    int row = g >> 6, c4 = g & 63;
    float4 f = *(const float4*)(A + (size_t)(gm0 + row) * 256 + c4 * 4);
    bf16x4 hh;
    hh[0] = (__bf16)f.x; hh[1] = (__bf16)f.y;
    hh[2] = (__bf16)f.z; hh[3] = (__bf16)f.w;
    *(bf16x4*)(&As[row * LDSP + c4 * 4]) = hh;
  }
  __syncthreads();

  f32x4 acc[4][2];
#pragma unroll
  for (int mt = 0; mt < 4; ++mt)
#pragma unroll
    for (int nt = 0; nt < 2; ++nt) acc[mt][nt] = (f32x4){0.f, 0.f, 0.f, 0.f};

#pragma unroll
  for (int kt = 0; kt < 8; ++kt) {
    const int ko = kt * 32 + q * 8;
    bf16x8 a[4], b[2];
#pragma unroll
    for (int mt = 0; mt < 4; ++mt)
      a[mt] = *(const bf16x8*)(&As[(mt * 16 + r) * LDSP + ko]);
#pragma unroll
    for (int nt = 0; nt < 2; ++nt)
      b[nt] = *(const bf16x8*)(BT + (size_t)(wn + nt * 16 + r) * 256 + ko);
#pragma unroll
    for (int mt = 0; mt < 4; ++mt)
#pragma unroll
      for (int nt = 0; nt < 2; ++nt)
        acc[mt][nt] =
            __builtin_amdgcn_mfma_f32_16x16x32_bf16(a[mt], b[nt], acc[mt][nt], 0, 0, 0);
  }

  __syncthreads();  // all As reads drained -> safe to overwrite as Asv

  // epilogue stage 1: scatter acc into LDS head-planar tile.
  // head == wave for this wave's cols; slot = wave*64 + row_local.
#pragma unroll
  for (int mt = 0; mt < 4; ++mt)
#pragma unroll
    for (int nt = 0; nt < 2; ++nt)
#pragma unroll
      for (int rr = 0; rr < 4; ++rr) {
        int row_local = mt * 16 + q * 4 + rr;
        int c = nt * 16 + r;
        Asv[(wave * 64 + row_local) * 32 + c] =
            (_Float16)(acc[mt][nt][rr] + bias[wn + c]);
      }
  __syncthreads();

  // epilogue stage 2: coalesced 64B per thread. thread t -> head t>>6, row t&63.
  {
    const _Float16* src = Asv + (size_t)t * 32;
    _Float16* dst = v + ((size_t)(t >> 6) * M + gm0 + (t & 63)) * 32;
#pragma unroll
    for (int j = 0; j < 4; ++j)
      *(f16x8*)(dst + j * 8) = *(const f16x8*)(src + j * 8);
  }
}

// ---------------- K2: oa GEMM + sampling + output GEMM, fully fused ----------------
// EXACT R8 config (best measured: ~42 us; VGPR 116). 64 queries, 256 threads,
// 2 blocks/CU. Occupancy scaling falsified THREE times (R4, R9: +35% occ -> 15%
// SLOWER): phase 3 is MSHR x L2-latency bound per CU; extra waves only queue.
// Residual prefetch (R8) saves 16 MB HBM.
__global__ __launch_bounds__(256, 2) void oa_sample_out(
    const float* __restrict__ query, const __bf16* __restrict__ btoa,
    const float* __restrict__ bias96, const _Float16* __restrict__ v,
    const _Float16* __restrict__ bto, const float* __restrict__ b_out,
    float* __restrict__ out, int M) {
  const int t = threadIdx.x;
  const int lane = t & 63;
  const int wave = t >> 6;
  const int r = lane & 15;
  const int q = lane >> 4;
  const int gm0 = blockIdx.x * 64;

  __shared__ __bf16 As[64 * LDSP];
  __shared__ float oas[64 * 100];
  _Float16* Asf = (_Float16*)As;  // phase 3/4 reuse As as f16 attn tile

  // ---- phase 1: stage query (64 x 256 fp32 -> bf16) ----
#pragma unroll
  for (int i = 0; i < 16; ++i) {
    int g = i * 256 + t;
    int row = g >> 6, c4 = g & 63;
    float4 f = *(const float4*)(query + (size_t)(gm0 + row) * 256 + c4 * 4);
    bf16x4 hh;
    hh[0] = (__bf16)f.x; hh[1] = (__bf16)f.y;
    hh[2] = (__bf16)f.z; hh[3] = (__bf16)f.w;
    *(bf16x4*)(&As[row * LDSP + c4 * 4]) = hh;
  }

  // ---- residual prefetch: this thread's 64 phase-4 output elements, fp32.
  // Tile just fetched -> L1/L2 hits, saves the 32MB HBM re-read (R8: FETCH 65->49MB).
  float resid[4][4][4];
#pragma unroll
  for (int mt = 0; mt < 4; ++mt)
#pragma unroll
    for (int nt = 0; nt < 4; ++nt)
#pragma unroll
      for (int rr = 0; rr < 4; ++rr)
        resid[mt][nt][rr] =
            query[(size_t)(gm0 + mt * 16 + q * 4 + rr) * 256 + wave * 64 + nt * 16 + r];

  __syncthreads();

  // ---- phase 2: oa GEMM (wave: 2 m-tiles x 3 n-tiles) ----
  {
    const int wm = (wave & 1) * 32;
    const int n0 = (wave >> 1) * 48;
    f32x4 acc[2][3];
#pragma unroll
    for (int mt = 0; mt < 2; ++mt)
#pragma unroll
      for (int nt = 0; nt < 3; ++nt) acc[mt][nt] = (f32x4){0.f, 0.f, 0.f, 0.f};
#pragma unroll
    for (int kt = 0; kt < 8; ++kt) {
      const int ko = kt * 32 + q * 8;
      bf16x8 a0 = *(const bf16x8*)(&As[(wm + r) * LDSP + ko]);
      bf16x8 a1 = *(const bf16x8*)(&As[(wm + 16 + r) * LDSP + ko]);
      bf16x8 b[3];
#pragma unroll
      for (int nt = 0; nt < 3; ++nt)
        b[nt] = *(const bf16x8*)(btoa + (size_t)(n0 + nt * 16 + r) * 256 + ko);
#pragma unroll
      for (int nt = 0; nt < 3; ++nt) {
        acc[0][nt] = __builtin_amdgcn_mfma_f32_16x16x32_bf16(a0, b[nt], acc[0][nt], 0, 0, 0);
        acc[1][nt] = __builtin_amdgcn_mfma_f32_16x16x32_bf16(a1, b[nt], acc[1][nt], 0, 0, 0);
      }
    }
#pragma unroll
    for (int mt = 0; mt < 2; ++mt)
#pragma unroll
      for (int nt = 0; nt < 3; ++nt)
#pragma unroll
        for (int rr = 0; rr < 4; ++rr) {
          int rl = wm + mt * 16 + q * 4 + rr;
          int col = n0 + nt * 16 + r;
          oas[rl * 100 + col] = acc[mt][nt][rr] + bias96[col];
        }
  }
  __syncthreads();  // oas ready; all As reads drained -> As reusable

  // ---- phase 3: sample 64 queries, write f16 attn tile into As ----
  {
    const int qrow = t >> 2;
    const int c8 = (t & 3) * 8;
    const int row = gm0 + qrow;
    const int b = row >> 14;  // nq = 16384
    const int qi = row & (NQ - 1);
    const int x = qi & (W_IMG - 1);
    const int y = qi >> 7;
    const float* oar = &oas[qrow * 100];
#pragma unroll
    for (int h = 0; h < NH; ++h) {
      float l0 = oar[64 + h * 4 + 0];
      float l1 = oar[64 + h * 4 + 1];
      float l2 = oar[64 + h * 4 + 2];
      float l3 = oar[64 + h * 4 + 3];
      float mx = fmaxf(fmaxf(l0, l1), fmaxf(l2, l3));
      float e0 = __expf(l0 - mx), e1 = __expf(l1 - mx);
      float e2 = __expf(l2 - mx), e3 = __expf(l3 - mx);
      float inv = 1.f / (e0 + e1 + e2 + e3);
      float awp[4] = {e0 * inv, e1 * inv, e2 * inv, e3 * inv};

      // -- stage 1: all 16 byte-offsets + weights --
      int offs[16];
      float wvs[16];
#pragma unroll
      for (int p = 0; p < NP; ++p) {
        float ox = oar[h * 8 + p * 2 + 0];
        float oy = oar[h * 8 + p * 2 + 1];
        float ix = (float)x + ox;
        float iy = (float)y + oy;
        float x0f = floorf(ix), y0f = floorf(iy);
        float wx1 = ix - x0f, wy1 = iy - y0f;
        int x0 = (int)x0f, y0 = (int)y0f;
        float wgt[4] = {(1.f - wx1) * (1.f - wy1), wx1 * (1.f - wy1),
                        (1.f - wx1) * wy1, wx1 * wy1};
        int xs[4] = {x0, x0 + 1, x0, x0 + 1};
        int ysv[4] = {y0, y0, y0 + 1, y0 + 1};
#pragma unroll
        for (int c = 0; c < 4; ++c) {
          int xi = xs[c], yi = ysv[c];
          bool valid = (xi >= 0) & (xi < W_IMG) & (yi >= 0) & (yi < H_IMG);
          int xc = xi < 0 ? 0 : (xi > W_IMG - 1 ? W_IMG - 1 : xi);
          int yc = yi < 0 ? 0 : (yi > H_IMG - 1 ? H_IMG - 1 : yi);
          offs[p * 4 + c] = (yc * W_IMG + xc) * (DH * 2);  // byte offset into head plane
          wvs[p * 4 + c] = awp[p] * wgt[c] * (valid ? 1.f : 0.f);
        }
      }

      // -- stage 2: issue all 16 loads as a batch --
      const char* vb =
          (const char*)v + ((size_t)h * M + (size_t)b * NQ) * (DH * 2) + c8 * 2;
      f16x8 g[16];
#pragma unroll
      for (int i = 0; i < 16; ++i) g[i] = *(const f16x8*)(vb + offs[i]);

      // -- stage 3: accumulate in packed f16 (v_pk_fma_f16) --
      f16x8 fa = {};
#pragma unroll
      for (int i = 0; i < 16; ++i) fa += g[i] * (_Float16)wvs[i];

      *(f16x8*)(&Asf[qrow * LDSP + h * DH + c8]) = fa;
    }
  }
  __syncthreads();  // f16 attn tile ready in As

  // ---- phase 4: out GEMM f16 (wave: all 64 rows x 64 cols = 4x4 tiles) ----
  {
    const int wn = wave * 64;
    f32x4 acc[4][4];
#pragma unroll
    for (int mt = 0; mt < 4; ++mt)
#pragma unroll
      for (int nt = 0; nt < 4; ++nt) acc[mt][nt] = (f32x4){0.f, 0.f, 0.f, 0.f};
#pragma unroll
    for (int kt = 0; kt < 8; ++kt) {
      const int ko = kt * 32 + q * 8;
      f16x8 a[4], b[4];
#pragma unroll
      for (int mt = 0; mt < 4; ++mt)
        a[mt] = *(const f16x8*)(&Asf[(mt * 16 + r) * LDSP + ko]);
#pragma unroll
      for (int nt = 0; nt < 4; ++nt)
        b[nt] = *(const f16x8*)(bto + (size_t)(wn + nt * 16 + r) * 256 + ko);
#pragma unroll
      for (int mt = 0; mt < 4; ++mt)
#pragma unroll
        for (int nt = 0; nt < 4; ++nt)
          acc[mt][nt] =
              __builtin_amdgcn_mfma_f32_16x16x32_f16(a[mt], b[nt], acc[mt][nt], 0, 0, 0);
    }
#pragma unroll
    for (int mt = 0; mt < 4; ++mt)
#pragma unroll
      for (int nt = 0; nt < 4; ++nt)
#pragma unroll
        for (int rr = 0; rr < 4; ++rr) {
          int row = gm0 + mt * 16 + q * 4 + rr;
          int col = wn + nt * 16 + r;
          out[(size_t)row * 256 + col] =
              acc[mt][nt][rr] + b_out[col] + resid[mt][nt][rr];
        }
  }
}

extern "C" void kernel_launch(void* const* d_in, const int* in_sizes, int n_in,
                              void* d_out, int out_size, void* d_ws, size_t ws_size,
                              hipStream_t stream) {
  const float* query  = (const float*)d_in[0];
  const float* value  = (const float*)d_in[1];
  const float* W_off  = (const float*)d_in[2];
  const float* b_off  = (const float*)d_in[3];
  const float* W_attn = (const float*)d_in[4];
  const float* b_attn = (const float*)d_in[5];
  const float* W_val  = (const float*)d_in[6];
  const float* b_val  = (const float*)d_in[7];
  const float* W_out  = (const float*)d_in[8];
  const float* b_out  = (const float*)d_in[9];
  float* out = (float*)d_out;

  char* ws = (char*)d_ws;
  __bf16*   btv    = (__bf16*)(ws + 0);          // 128 KB
  _Float16* bto    = (_Float16*)(ws + 131072);   // 128 KB
  __bf16*   btoa   = (__bf16*)(ws + 262144);     // 48 KB
  float*    bias96 = (float*)(ws + 311296);      // 384 B
  _Float16* v      = (_Float16*)(ws + 524288);   // 16 MB (f16, head-planar)

  const int M = in_sizes[0] / CIN;  // 32768 = bs * nq

  prep_weights<<<256, 256, 0, stream>>>(W_val, W_out, W_off, W_attn,
                                        b_off, b_attn, btv, bto, btoa, bias96);
  gemm_v<<<M / 64, 512, 0, stream>>>(value, btv, b_val, v, M);
  oa_sample_out<<<M / 64, 256, 0, stream>>>(query, btoa, bias96, v, bto, b_out, out, M);
}

// Round 12
// 158.323 us; speedup vs baseline: 1.0316x; 1.0316x over previous
//
#include <hip/hip_runtime.h>

#define H_IMG 128
#define W_IMG 128
#define NQ (H_IMG * W_IMG)
#define CIN 256
#define NH 8
#define NP 4
#define DH 32
#define LDSP 264  // padded LDS row stride (16-bit elems); 264%32=8 -> 2-way max aliasing (free)

typedef __bf16 bf16x4 __attribute__((ext_vector_type(4)));
typedef __bf16 bf16x8 __attribute__((ext_vector_type(8)));
typedef _Float16 f16x8 __attribute__((ext_vector_type(8)));
typedef float f32x4 __attribute__((ext_vector_type(4)));

// ---------------- weight prep: transpose to BT[N][K]; btv/btoa bf16, bto f16 -------
__global__ __launch_bounds__(256) void prep_weights(
    const float* __restrict__ Wval, const float* __restrict__ Wout,
    const float* __restrict__ Woff, const float* __restrict__ Wattn,
    const float* __restrict__ boff, const float* __restrict__ battn,
    __bf16* __restrict__ btv, _Float16* __restrict__ bto,
    __bf16* __restrict__ btoa, float* __restrict__ bias96) {
  int id = blockIdx.x * 256 + threadIdx.x;
  if (id < 256 * 256) {
    int n = id >> 8, k = id & 255;
    btv[n * 256 + k] = (__bf16)Wval[k * 256 + n];
    bto[n * 256 + k] = (_Float16)Wout[k * 256 + n];
  }
  if (id < 96 * 256) {
    int n = id >> 8, k = id & 255;
    float w = (n < 64) ? Woff[k * 64 + n] : Wattn[k * 32 + (n - 64)];
    btoa[n * 256 + k] = (__bf16)w;
  }
  if (id < 96) {
    bias96[id] = (id < 64) ? boff[id] : battn[id - 64];
  }
}

// ---------------- K1: v = value @ W_val + b_val (head-planar f16 out) --------------
// N-SPLIT this round: 1024 blocks; block b does rows (b&511)*64, cols (b>>9)*128.
// XCD affinity preserved BY CONSTRUCTION: both producers of row-panel p are blocks
// p and p+512, and 512%8==0 -> both on XCD p%8 = the consumer K2-block's XCD
// (the R5/R7-verified constraint). LDS 34KB -> 4 blocks/CU; bounds(512,8) caps
// VGPR at 64 (genuine need ~55: acc 16 + a-frags 16 + addressing -> no R1 spill).
// 32 waves/CU on a streaming GEMM = the wave-responsive regime (R5/R10 evidence).
// Cost: A tile read twice (blocks p and p+512); second read is L2/L3-hot.
// Epilogue: R10-style scalar scatter (R11 proved the LDS-staged version is no better).
__global__ __launch_bounds__(512, 8) void gemm_v(
    const float* __restrict__ A, const __bf16* __restrict__ BT,
    const float* __restrict__ bias, _Float16* __restrict__ v, int M) {
  const int t = threadIdx.x;
  const int lane = t & 63;
  const int wave = t >> 6;  // 0..7
  const int r = lane & 15;
  const int q = lane >> 4;
  const int b = blockIdx.x;
  const int gm0 = (b & 511) * 64;            // row panel (identity -> affinity)
  const int wn = (b >> 9) * 128 + wave * 16; // 16-col slice per wave

  __shared__ __bf16 As[64 * LDSP];

  // stage A (64 x 256 fp32 -> bf16), 512 threads, coalesced, conflict-free
#pragma unroll
  for (int i = 0; i < 8; ++i) {
    int g = i * 512 + t;
    int row = g >> 6, c4 = g & 63;
    float4 f = *(const float4*)(A + (size_t)(gm0 + row) * 256 + c4 * 4);
    bf16x4 hh;
    hh[0] = (__bf16)f.x; hh[1] = (__bf16)f.y;
    hh[2] = (__bf16)f.z; hh[3] = (__bf16)f.w;
    *(bf16x4*)(&As[row * LDSP + c4 * 4]) = hh;
  }
  __syncthreads();

  f32x4 acc[4];
#pragma unroll
  for (int mt = 0; mt < 4; ++mt) acc[mt] = (f32x4){0.f, 0.f, 0.f, 0.f};

#pragma unroll
  for (int kt = 0; kt < 8; ++kt) {
    const int ko = kt * 32 + q * 8;
    bf16x8 a[4];
#pragma unroll
    for (int mt = 0; mt < 4; ++mt)
      a[mt] = *(const bf16x8*)(&As[(mt * 16 + r) * LDSP + ko]);
    bf16x8 bb = *(const bf16x8*)(BT + (size_t)(wn + r) * 256 + ko);
#pragma unroll
    for (int mt = 0; mt < 4; ++mt)
      acc[mt] = __builtin_amdgcn_mfma_f32_16x16x32_bf16(a[mt], bb, acc[mt], 0, 0, 0);
  }

  // epilogue: head-planar scatter v[head][row][col&31] (f16)
#pragma unroll
  for (int mt = 0; mt < 4; ++mt)
#pragma unroll
    for (int rr = 0; rr < 4; ++rr) {
      int row = gm0 + mt * 16 + q * 4 + rr;
      int col = wn + r;
      v[((size_t)(col >> 5) * M + row) * 32 + (col & 31)] =
          (_Float16)(acc[mt][rr] + bias[col]);
    }
}

// ---------------- K2: oa GEMM + sampling + output GEMM, fully fused ----------------
// EXACT R8 config (best measured: ~41.5 us; VGPR 116). 64 queries, 256 threads,
// 2 blocks/CU. Occupancy scaling falsified THREE times (R4, R9: +35% occ -> 15%
// SLOWER): phase 3 is a latency-bound gather per CU; extra waves only queue.
// Residual prefetch (R8) saves 16 MB HBM.
__global__ __launch_bounds__(256, 2) void oa_sample_out(
    const float* __restrict__ query, const __bf16* __restrict__ btoa,
    const float* __restrict__ bias96, const _Float16* __restrict__ v,
    const _Float16* __restrict__ bto, const float* __restrict__ b_out,
    float* __restrict__ out, int M) {
  const int t = threadIdx.x;
  const int lane = t & 63;
  const int wave = t >> 6;
  const int r = lane & 15;
  const int q = lane >> 4;
  const int gm0 = blockIdx.x * 64;

  __shared__ __bf16 As[64 * LDSP];
  __shared__ float oas[64 * 100];
  _Float16* Asf = (_Float16*)As;  // phase 3/4 reuse As as f16 attn tile

  // ---- phase 1: stage query (64 x 256 fp32 -> bf16) ----
#pragma unroll
  for (int i = 0; i < 16; ++i) {
    int g = i * 256 + t;
    int row = g >> 6, c4 = g & 63;
    float4 f = *(const float4*)(query + (size_t)(gm0 + row) * 256 + c4 * 4);
    bf16x4 hh;
    hh[0] = (__bf16)f.x; hh[1] = (__bf16)f.y;
    hh[2] = (__bf16)f.z; hh[3] = (__bf16)f.w;
    *(bf16x4*)(&As[row * LDSP + c4 * 4]) = hh;
  }

  // ---- residual prefetch: this thread's 64 phase-4 output elements, fp32.
  // Tile just fetched -> L1/L2 hits, saves the 32MB HBM re-read (R8: FETCH 65->49MB).
  float resid[4][4][4];
#pragma unroll
  for (int mt = 0; mt < 4; ++mt)
#pragma unroll
    for (int nt = 0; nt < 4; ++nt)
#pragma unroll
      for (int rr = 0; rr < 4; ++rr)
        resid[mt][nt][rr] =
            query[(size_t)(gm0 + mt * 16 + q * 4 + rr) * 256 + wave * 64 + nt * 16 + r];

  __syncthreads();

  // ---- phase 2: oa GEMM (wave: 2 m-tiles x 3 n-tiles) ----
  {
    const int wm = (wave & 1) * 32;
    const int n0 = (wave >> 1) * 48;
    f32x4 acc[2][3];
#pragma unroll
    for (int mt = 0; mt < 2; ++mt)
#pragma unroll
      for (int nt = 0; nt < 3; ++nt) acc[mt][nt] = (f32x4){0.f, 0.f, 0.f, 0.f};
#pragma unroll
    for (int kt = 0; kt < 8; ++kt) {
      const int ko = kt * 32 + q * 8;
      bf16x8 a0 = *(const bf16x8*)(&As[(wm + r) * LDSP + ko]);
      bf16x8 a1 = *(const bf16x8*)(&As[(wm + 16 + r) * LDSP + ko]);
      bf16x8 b[3];
#pragma unroll
      for (int nt = 0; nt < 3; ++nt)
        b[nt] = *(const bf16x8*)(btoa + (size_t)(n0 + nt * 16 + r) * 256 + ko);
#pragma unroll
      for (int nt = 0; nt < 3; ++nt) {
        acc[0][nt] = __builtin_amdgcn_mfma_f32_16x16x32_bf16(a0, b[nt], acc[0][nt], 0, 0, 0);
        acc[1][nt] = __builtin_amdgcn_mfma_f32_16x16x32_bf16(a1, b[nt], acc[1][nt], 0, 0, 0);
      }
    }
#pragma unroll
    for (int mt = 0; mt < 2; ++mt)
#pragma unroll
      for (int nt = 0; nt < 3; ++nt)
#pragma unroll
        for (int rr = 0; rr < 4; ++rr) {
          int rl = wm + mt * 16 + q * 4 + rr;
          int col = n0 + nt * 16 + r;
          oas[rl * 100 + col] = acc[mt][nt][rr] + bias96[col];
        }
  }
  __syncthreads();  // oas ready; all As reads drained -> As reusable

  // ---- phase 3: sample 64 queries, write f16 attn tile into As ----
  {
    const int qrow = t >> 2;
    const int c8 = (t & 3) * 8;
    const int row = gm0 + qrow;
    const int b = row >> 14;  // nq = 16384
    const int qi = row & (NQ - 1);
    const int x = qi & (W_IMG - 1);
    const int y = qi >> 7;
    const float* oar = &oas[qrow * 100];
#pragma unroll
    for (int h = 0; h < NH; ++h) {
      float l0 = oar[64 + h * 4 + 0];
      float l1 = oar[64 + h * 4 + 1];
      float l2 = oar[64 + h * 4 + 2];
      float l3 = oar[64 + h * 4 + 3];
      float mx = fmaxf(fmaxf(l0, l1), fmaxf(l2, l3));
      float e0 = __expf(l0 - mx), e1 = __expf(l1 - mx);
      float e2 = __expf(l2 - mx), e3 = __expf(l3 - mx);
      float inv = 1.f / (e0 + e1 + e2 + e3);
      float awp[4] = {e0 * inv, e1 * inv, e2 * inv, e3 * inv};

      // -- stage 1: all 16 byte-offsets + weights --
      int offs[16];
      float wvs[16];
#pragma unroll
      for (int p = 0; p < NP; ++p) {
        float ox = oar[h * 8 + p * 2 + 0];
        float oy = oar[h * 8 + p * 2 + 1];
        float ix = (float)x + ox;
        float iy = (float)y + oy;
        float x0f = floorf(ix), y0f = floorf(iy);
        float wx1 = ix - x0f, wy1 = iy - y0f;
        int x0 = (int)x0f, y0 = (int)y0f;
        float wgt[4] = {(1.f - wx1) * (1.f - wy1), wx1 * (1.f - wy1),
                        (1.f - wx1) * wy1, wx1 * wy1};
        int xs[4] = {x0, x0 + 1, x0, x0 + 1};
        int ysv[4] = {y0, y0, y0 + 1, y0 + 1};
#pragma unroll
        for (int c = 0; c < 4; ++c) {
          int xi = xs[c], yi = ysv[c];
          bool valid = (xi >= 0) & (xi < W_IMG) & (yi >= 0) & (yi < H_IMG);
          int xc = xi < 0 ? 0 : (xi > W_IMG - 1 ? W_IMG - 1 : xi);
          int yc = yi < 0 ? 0 : (yi > H_IMG - 1 ? H_IMG - 1 : yi);
          offs[p * 4 + c] = (yc * W_IMG + xc) * (DH * 2);  // byte offset into head plane
          wvs[p * 4 + c] = awp[p] * wgt[c] * (valid ? 1.f : 0.f);
        }
      }

      // -- stage 2: issue all 16 loads as a batch --
      const char* vb =
          (const char*)v + ((size_t)h * M + (size_t)b * NQ) * (DH * 2) + c8 * 2;
      f16x8 g[16];
#pragma unroll
      for (int i = 0; i < 16; ++i) g[i] = *(const f16x8*)(vb + offs[i]);

      // -- stage 3: accumulate in packed f16 (v_pk_fma_f16) --
      f16x8 fa = {};
#pragma unroll
      for (int i = 0; i < 16; ++i) fa += g[i] * (_Float16)wvs[i];

      *(f16x8*)(&Asf[qrow * LDSP + h * DH + c8]) = fa;
    }
  }
  __syncthreads();  // f16 attn tile ready in As

  // ---- phase 4: out GEMM f16 (wave: all 64 rows x 64 cols = 4x4 tiles) ----
  {
    const int wn = wave * 64;
    f32x4 acc[4][4];
#pragma unroll
    for (int mt = 0; mt < 4; ++mt)
#pragma unroll
      for (int nt = 0; nt < 4; ++nt) acc[mt][nt] = (f32x4){0.f, 0.f, 0.f, 0.f};
#pragma unroll
    for (int kt = 0; kt < 8; ++kt) {
      const int ko = kt * 32 + q * 8;
      f16x8 a[4], b[4];
#pragma unroll
      for (int mt = 0; mt < 4; ++mt)
        a[mt] = *(const f16x8*)(&Asf[(mt * 16 + r) * LDSP + ko]);
#pragma unroll
      for (int nt = 0; nt < 4; ++nt)
        b[nt] = *(const f16x8*)(bto + (size_t)(wn + nt * 16 + r) * 256 + ko);
#pragma unroll
      for (int mt = 0; mt < 4; ++mt)
#pragma unroll
        for (int nt = 0; nt < 4; ++nt)
          acc[mt][nt] =
              __builtin_amdgcn_mfma_f32_16x16x32_f16(a[mt], b[nt], acc[mt][nt], 0, 0, 0);
    }
#pragma unroll
    for (int mt = 0; mt < 4; ++mt)
#pragma unroll
      for (int nt = 0; nt < 4; ++nt)
#pragma unroll
        for (int rr = 0; rr < 4; ++rr) {
          int row = gm0 + mt * 16 + q * 4 + rr;
          int col = wn + nt * 16 + r;
          out[(size_t)row * 256 + col] =
              acc[mt][nt][rr] + b_out[col] + resid[mt][nt][rr];
        }
  }
}

extern "C" void kernel_launch(void* const* d_in, const int* in_sizes, int n_in,
                              void* d_out, int out_size, void* d_ws, size_t ws_size,
                              hipStream_t stream) {
  const float* query  = (const float*)d_in[0];
  const float* value  = (const float*)d_in[1];
  const float* W_off  = (const float*)d_in[2];
  const float* b_off  = (const float*)d_in[3];
  const float* W_attn = (const float*)d_in[4];
  const float* b_attn = (const float*)d_in[5];
  const float* W_val  = (const float*)d_in[6];
  const float* b_val  = (const float*)d_in[7];
  const float* W_out  = (const float*)d_in[8];
  const float* b_out  = (const float*)d_in[9];
  float* out = (float*)d_out;

  char* ws = (char*)d_ws;
  __bf16*   btv    = (__bf16*)(ws + 0);          // 128 KB
  _Float16* bto    = (_Float16*)(ws + 131072);   // 128 KB
  __bf16*   btoa   = (__bf16*)(ws + 262144);     // 48 KB
  float*    bias96 = (float*)(ws + 311296);      // 384 B
  _Float16* v      = (_Float16*)(ws + 524288);   // 16 MB (f16, head-planar)

  const int M = in_sizes[0] / CIN;  // 32768 = bs * nq

  prep_weights<<<256, 256, 0, stream>>>(W_val, W_out, W_off, W_attn,
                                        b_off, b_attn, btv, bto, btoa, bias96);
  gemm_v<<<(M / 64) * 2, 512, 0, stream>>>(value, btv, b_val, v, M);
  oa_sample_out<<<M / 64, 256, 0, stream>>>(query, btoa, bias96, v, bto, b_out, out, M);
}